// Round 13
// baseline (335.426 us; speedup 1.0000x reference)
//
#include <hip/hip_runtime.h>

#define NSTEPS 730
#define NGRID  10000
#define LENF   15
#define NEARZERO 1e-5f
#define KB 10            // steps per pipeline block
#define NBLK 73          // 730 = 73 * 10
#define NROUND (NBLK + 3)  // 76: B soils block m; C FIRs m-2, stores m-3

struct F3 { float p, t, e; };  // (prcp, tmean, pet), 12B

// 2-role pipeline with raw-barrier sync (round-11 structure + round-9
// sync mechanics). Resubmission of round 12: that bench died with
// "container failed twice" (infra; no pytest/dispatch evidence). Kernel
// re-audited: uniform barrier count (no hang), compiler-visible loads
// (auto-waits guarantee correctness; manual vmcnt only adds constraints),
// LDS ring-6 write/read/rewrite separation verified both parities.
//
// Round-11 failure analysis: correct output (absmax 0.03125) but 235us --
// __syncthreads' implied `s_waitcnt vmcnt(0)` drained the in-flight
// prefetch ON the critical wave every 2 rounds, plus conservative
// auto-waits; in the 3-role these costs sat on slack-rich wave A.
// Fixes here (all individually proven in round 9, which PASSED):
//  - raw __builtin_amdgcn_s_barrier() every 2 rounds (no vmcnt drain)
//  - B: asm vmcnt(20) before SOIL (block m's loads have exactly 20 newer:
//    batches m+1, m+2), leaving the newest 20 loads in flight
//  - B: lgkmcnt(0) before each barrier (q_buf visibility to C)
// Ring-6 safety: slot s=m%6 written round m, read round m+2 (barrier at
// the odd round between always separates), rewritten round m+6 (>=2
// barriers after the read). Store/FIR parity disjoint each round.
//
//   Wave B (wid 0): reg-ring-3 input prefetch + snow + soil -> q LDS ring
//                   (snow's ~10-op chain runs inside soil's log/exp
//                    latency shadows: adds ZERO to the carried cycle)
//   Wave C (wid 1): 15-tap FIR + one-round-delayed stores
__global__ __launch_bounds__(128, 1) void hbv_pipe2(const float* __restrict__ xp,
                                                    const float* __restrict__ ps,
                                                    float* __restrict__ out) {
    __shared__ float q_buf[6][KB][64];   // B -> C : q, 6-slot ring, 15360B

    const int lane = threadIdx.x & 63;
    const int wid  = threadIdx.x >> 6;
    int g = blockIdx.x * 64 + lane;
    g = (g < NGRID) ? g : (NGRID - 1);   // clamp: dup work, benign
    const int pb = g * 16;
    const F3* __restrict__ xv = (const F3*)xp;

    // ---- role B state ----
    float aTT = 0, aCFMAX = 0, aCFRxCFMAX = 0, aCWH = 0;
    float snow = NEARZERO, melt = NEARZERO;
    float bFC = 0, bBETA = 0, bB1 = 0, bBETAET = 0, bB2 = 0, bInvFC = 0,
          bC = 0, bPERC = 0, bK0 = 0, bK1 = 0, bK2 = 0, bUZL = 0;
    float sm = NEARZERO, suz = NEARZERO, slz = NEARZERO;
    F3 bufA[KB], bufB[KB], bufC[KB];     // reg ring, static names only
    // ---- role C state ----
    float w[LENF];
    float r[LENF - 1];
    float outvE[KB], outvO[KB];          // delayed-store double buffer

    if (wid == 0) {
        aTT        = ps[pb + 8]  * 5.0f - 2.5f;
        aCFMAX     = ps[pb + 9]  * 9.5f + 0.5f;
        aCFRxCFMAX = (ps[pb + 10] * 0.1f) * aCFMAX;
        aCWH       = ps[pb + 11] * 0.2f;
        bFC     = ps[pb + 1]  * 950.0f + 50.0f;
        bBETA   = ps[pb + 0]  * 5.0f   + 1.0f;
        float LP = ps[pb + 5] * 0.8f   + 0.2f;
        bBETAET = ps[pb + 12] * 4.7f   + 0.3f;
        bInvFC  = 1.0f / bFC;
        // fold the argument scaling into the log: log2(x/FC)=log2(x)-log2(FC)
        bB1 = -bBETA   * __builtin_amdgcn_logf(bFC);
        bB2 = -bBETAET * __builtin_amdgcn_logf(LP * bFC);
        bC   = ps[pb + 13];
        bPERC = ps[pb + 6] * 10.0f;
        bK0  = ps[pb + 2] * 0.85f  + 0.05f;
        bK1  = ps[pb + 3] * 0.49f  + 0.01f;
        bK2  = ps[pb + 4] * 0.199f + 0.001f;
        bUZL = ps[pb + 7] * 100.0f;
    } else {
        // routing weights; -lgamma(aa)-aa*log(theta) cancel under normalization
        const float LOG2E = 1.4426950408889634f;
        float aa    = fmaxf(ps[pb + 14] * 2.9f, 0.0f) + 0.1f;
        float theta = fmaxf(ps[pb + 15] * 6.5f, 0.0f) + 0.5f;
        float sc = LOG2E / theta, am1 = aa - 1.0f, wsum = 0.0f;
#pragma unroll
        for (int k = 0; k < LENF; ++k) {
            float tg = (float)k + 0.5f;
            w[k] = __builtin_amdgcn_exp2f(am1 * __builtin_amdgcn_logf(tg) - tg * sc);
            wsum += w[k];
        }
        float inv = 1.0f / wsum;
#pragma unroll
        for (int k = 0; k < LENF; ++k) w[k] *= inv;
#pragma unroll
        for (int j = 0; j < LENF - 1; ++j) r[j] = 0.0f;
    }

    auto LOADIN = [&](F3* buf, int blk) {
#pragma unroll
        for (int i = 0; i < KB; ++i)
            buf[i] = xv[(size_t)(blk * KB + i) * NGRID + g];
    };

    // snow + soil for one block; q written to the LDS ring slot b%6.
    auto SOIL = [&](const F3* in, int b) {
        float (*qp)[64] = q_buf[b % 6];
#pragma unroll
        for (int i = 0; i < KB; ++i) {
            float p = in[i].p, tm = in[i].t, pe = in[i].e;
            float dt = tm - aTT;
            float rain = (dt >= 0.0f) ? p : 0.0f;
            float mm = fmaxf(aCFMAX * dt, 0.0f);
            float rr = fmaxf(-aCFRxCFMAX * dt, 0.0f);
            snow += p - rain;
            float mq = fminf(mm, snow);
            melt += mq; snow -= mq;
            float refr = fminf(rr, melt);
            snow += refr; melt -= refr;
            float tosoil = fmaxf(fmaf(-aCWH, snow, melt), 0.0f);
            melt -= tosoil;
            float rt = rain + tosoil;

            // soil/runoff: the irreducible carried cycle
            float l1  = __builtin_amdgcn_logf(sm);
            float sw  = fminf(__builtin_amdgcn_exp2f(fmaf(bBETA, l1, bB1)), 1.0f);
            float smp = sm + rt;
            float sm1 = fmaf(-rt, sw, smp);
            float rch = rt * sw;
            float sm2 = fminf(sm1, bFC);
            float exc = fmaxf(sm1 - bFC, 0.0f);
            float l2  = __builtin_amdgcn_logf(sm2);
            float ef  = fminf(__builtin_amdgcn_exp2f(fmaf(bBETAET, l2, bB2)), 1.0f);
            float sm3 = fmaxf(fmaf(-pe, ef, sm2), NEARZERO);
            float d   = fmaxf(fmaf(-bInvFC, sm3, 1.0f), 0.0f);
            float cz  = bC * slz;
            float cap = cz * d;               // == min(slz, cz*d): C<=1, d<=1
            sm = sm3 + cap;
            float slz1 = fmaxf(slz - cap, NEARZERO);
            float su1 = suz + rch + exc;
            float pa  = fminf(su1, bPERC);
            float su2 = su1 - pa;
            float q0  = bK0 * fmaxf(su2 - bUZL, 0.0f);
            float su3 = su2 - q0;
            float q1  = bK1 * su3;
            suz = su3 - q1;
            float sl2 = slz1 + pa;
            float q2  = bK2 * sl2;
            slz = sl2 - q2;
            qp[i][lane] = (q0 + q1) + q2;
        }
    };
    auto FIR = [&](float* ov, int b) {
        float (*qp)[64] = q_buf[b % 6];
        float qv[KB];
#pragma unroll
        for (int i = 0; i < KB; ++i) qv[i] = qp[i][lane];
#pragma unroll
        for (int i = 0; i < KB; ++i) {
            float q = qv[i];
            ov[i] = fmaf(w[0], q, r[0]);
#pragma unroll
            for (int j = 0; j < LENF - 2; ++j)
                r[j] = fmaf(w[j + 1], q, r[j + 1]);
            r[LENF - 2] = w[LENF - 1] * q;
        }
    };
    auto STORE = [&](const float* ov, int b) {
#pragma unroll
        for (int i = 0; i < KB; ++i)
            out[(size_t)(b * KB + i) * NGRID + g] = ov[i];
    };

    // prologue: blocks 0 and 1 in flight
    if (wid == 0) {
        LOADIN(bufA, 0);
        LOADIN(bufB, 1);
    }

    for (int m = 0; m < NROUND; ++m) {
        if (wid == 0) {
            const int ph = m % 3;   // block m lives in slot m%3
            // issue block m+2's loads first (consumed 2 rounds later)
            if (m + 2 < NBLK) {
                if (ph == 0)      LOADIN(bufC, m + 2);   // slot (m+2)%3 == 2
                else if (ph == 1) LOADIN(bufA, m + 2);   // slot 0
                else              LOADIN(bufB, m + 2);   // slot 1
            }
            // wait ONLY for block m's batch: newer = batches m+1, m+2
            {
                const int newer = ((m + 1 < NBLK) ? 10 : 0) +
                                  ((m + 2 < NBLK) ? 10 : 0);
                if (newer == 20)      asm volatile("s_waitcnt vmcnt(20)" ::: "memory");
                else if (newer == 10) asm volatile("s_waitcnt vmcnt(10)" ::: "memory");
                else                  asm volatile("s_waitcnt vmcnt(0)"  ::: "memory");
            }
            // snow+soil on block m (loaded 2 rounds ago)
            if (m < NBLK) {
                if (ph == 0)      SOIL(bufA, m);
                else if (ph == 1) SOIL(bufB, m);
                else              SOIL(bufC, m);
            }
        } else {
            // store block m-3 first (regs written last round; fire-and-forget)
            if (m >= 3 && m <= NBLK + 2) {
                const int bs = m - 3;
                if ((bs & 1) == 0) STORE(outvE, bs);
                else               STORE(outvO, bs);
            }
            // FIR block m-2 into the other parity buffer
            if (m >= 2 && m <= NBLK + 1) {
                const int b = m - 2;
                if ((b & 1) == 0) FIR(outvE, b);
                else              FIR(outvO, b);
            }
        }
        if (m & 1) {
            // q_buf writes must be visible to C before it crosses the barrier
            if (wid == 0) asm volatile("s_waitcnt lgkmcnt(0)" ::: "memory");
            __builtin_amdgcn_s_barrier();   // raw: NO vmcnt drain
        }
    }
}

extern "C" void kernel_launch(void* const* d_in, const int* in_sizes, int n_in,
                              void* d_out, int out_size, void* d_ws, size_t ws_size,
                              hipStream_t stream) {
    const float* x_phy      = (const float*)d_in[0]; // f32 (730,10000,3)
    const float* phy_static = (const float*)d_in[1]; // f32 (10000,16)
    float* out = (float*)d_out;                      // f32 (730,10000)

    int nwg = (NGRID + 63) / 64;  // 157 workgroups x 128 threads (2 waves)
    hbv_pipe2<<<nwg, 128, 0, stream>>>(x_phy, phy_static, out);
}

// Round 14
// 204.127 us; speedup vs baseline: 1.6432x; 1.6432x over previous
//
#include <hip/hip_runtime.h>

#define NSTEPS 730
#define NGRID  10000
#define LENF   15
#define NEARZERO 1e-5f
#define KB 20            // steps per pipeline block (was 10)
#define NBLK 37          // ceil(730/20): block 36 is half-phantom (steps 720-739)
#define NROUND (NBLK + 4)

struct F3 { float p, t, e; };  // (prcp, tmean, pet), 12B

// R7 skeleton (best verified: 105us dispatch) with KB doubled 10->20.
// Rationale: R7/R8/R9 all sit at ~345 cy/step = chain (~230) + ~115/step of
// PER-ROUND overhead (batch ds_read+lgkm ~200, ds_write+lgkm ~100, barrier
// arrival spread ~300-500, loop control). R11/R13 proved sync flavor is
// second-order and the 2-role merge is a dead end; the remaining lever on
// the best kernel is amortization: KB=20 halves per-step round overhead.
// 730 = 36*20 + 10: block 36 computes 10 phantom steps (loads clamped to
// step 729, stores guarded t<730; phantom state/FIR results never stored).
//
//   Wave A: batch input prefetch (reg double-buffer) + snow chain -> LDS
//   Wave B: soil/runoff chain (irreducible serial core)          -> LDS
//   Wave C: transposed-FIR gamma routing, stores DELAYED one round
// Skew: A loads m; A snows m-1; B soils m-2; C FIRs m-3; C stores m-4.
// rtpe slot b&1: written round b+1, read b+2, rewritten b+3 (after read).
// q slot b&1: written b+2, read b+3, rewritten b+4. __syncthreads per round.
__global__ __launch_bounds__(192, 1) void hbv_pipe3(const float* __restrict__ xp,
                                                    const float* __restrict__ ps,
                                                    float* __restrict__ out) {
    __shared__ float2 rtpe_buf[2][KB][64];  // A -> B : (rain+tosoil, pet) 20.5KB
    __shared__ float  q_buf[2][KB][64];     // B -> C : q                  10.2KB

    const int lane = threadIdx.x & 63;
    const int wid  = threadIdx.x >> 6;
    int g = blockIdx.x * 64 + lane;
    g = (g < NGRID) ? g : (NGRID - 1);      // clamp: dup work, benign
    const int pb = g * 16;
    const F3* __restrict__ xv = (const F3*)xp;

    // ---- role A state ----
    float aTT = 0, aCFMAX = 0, aCFRxCFMAX = 0, aCWH = 0;
    float snow = NEARZERO, melt = NEARZERO;
    F3 abufA[KB], abufB[KB];               // static names only (no runtime idx)
    // ---- role B state ----
    float bFC = 0, bBETA = 0, bB1 = 0, bBETAET = 0, bB2 = 0, bInvFC = 0,
          bC = 0, bPERC = 0, bK0 = 0, bK1 = 0, bK2 = 0, bUZL = 0;
    float sm = NEARZERO, suz = NEARZERO, slz = NEARZERO;
    // ---- role C state ----
    float w[LENF];
    float r[LENF - 1];
    float outv[KB];

    if (wid == 0) {
        aTT        = ps[pb + 8]  * 5.0f - 2.5f;
        aCFMAX     = ps[pb + 9]  * 9.5f + 0.5f;
        aCFRxCFMAX = (ps[pb + 10] * 0.1f) * aCFMAX;
        aCWH       = ps[pb + 11] * 0.2f;
    } else if (wid == 1) {
        bFC     = ps[pb + 1]  * 950.0f + 50.0f;
        bBETA   = ps[pb + 0]  * 5.0f   + 1.0f;
        float LP = ps[pb + 5] * 0.8f   + 0.2f;
        bBETAET = ps[pb + 12] * 4.7f   + 0.3f;
        bInvFC  = 1.0f / bFC;
        // fold the argument scaling into the log: log2(x/FC)=log2(x)-log2(FC)
        bB1 = -bBETA   * __builtin_amdgcn_logf(bFC);
        bB2 = -bBETAET * __builtin_amdgcn_logf(LP * bFC);
        bC   = ps[pb + 13];
        bPERC = ps[pb + 6] * 10.0f;
        bK0  = ps[pb + 2] * 0.85f  + 0.05f;
        bK1  = ps[pb + 3] * 0.49f  + 0.01f;
        bK2  = ps[pb + 4] * 0.199f + 0.001f;
        bUZL = ps[pb + 7] * 100.0f;
    } else {
        // routing weights; -lgamma(aa)-aa*log(theta) cancel under normalization
        const float LOG2E = 1.4426950408889634f;
        float aa    = fmaxf(ps[pb + 14] * 2.9f, 0.0f) + 0.1f;
        float theta = fmaxf(ps[pb + 15] * 6.5f, 0.0f) + 0.5f;
        float sc = LOG2E / theta, am1 = aa - 1.0f, wsum = 0.0f;
#pragma unroll
        for (int k = 0; k < LENF; ++k) {
            float tg = (float)k + 0.5f;
            w[k] = __builtin_amdgcn_exp2f(am1 * __builtin_amdgcn_logf(tg) - tg * sc);
            wsum += w[k];
        }
        float inv = 1.0f / wsum;
#pragma unroll
        for (int k = 0; k < LENF; ++k) w[k] *= inv;
#pragma unroll
        for (int j = 0; j < LENF - 1; ++j) r[j] = 0.0f;
    }

    // batch prefetch; step index clamped to 729 for the phantom tail
    auto LOADIN = [&](F3* buf, int blk) {
#pragma unroll
        for (int i = 0; i < KB; ++i) {
            int t = blk * KB + i;
            t = (t < NSTEPS) ? t : (NSTEPS - 1);
            buf[i] = xv[(size_t)t * NGRID + g];
        }
    };
    // snow chain for one block (consumes a register buffer loaded last round)
    auto SNOW = [&](const F3* in, int b) {
        float2 (*rp)[64] = rtpe_buf[b & 1];
#pragma unroll
        for (int i = 0; i < KB; ++i) {
            float p = in[i].p, tm = in[i].t;
            float dt = tm - aTT;
            float rain = (dt >= 0.0f) ? p : 0.0f;
            float mm = fmaxf(aCFMAX * dt, 0.0f);
            float rr = fmaxf(-aCFRxCFMAX * dt, 0.0f);   // == aCFRxCFMAX*(aTT-tm)
            snow += p - rain;
            float mq = fminf(mm, snow);
            melt += mq; snow -= mq;
            float refr = fminf(rr, melt);
            snow += refr; melt -= refr;
            float tosoil = fmaxf(fmaf(-aCWH, snow, melt), 0.0f);
            melt -= tosoil;
            rp[i][lane] = make_float2(rain + tosoil, in[i].e);
        }
    };

    for (int m = 0; m < NROUND; ++m) {
        if (wid == 0) {
            // section A1: issue next block's loads FIRST (old by barrier)
            if (m < NBLK) {
                if ((m & 1) == 0) LOADIN(abufA, m);
                else              LOADIN(abufB, m);
            }
            __builtin_amdgcn_sched_barrier(0);
            // section A2: snow chain on the block loaded LAST round
            if (m >= 1 && m <= NBLK) {
                int b = m - 1;
                if ((b & 1) == 0) SNOW(abufA, b);
                else              SNOW(abufB, b);
            }
        } else if (wid == 1) {
            if (m >= 2 && m <= NBLK + 1) {
                int b = m - 2, slot = b & 1;
                float rt[KB], pe[KB];
#pragma unroll
                for (int i = 0; i < KB; ++i) {
                    float2 v = rtpe_buf[slot][i][lane];
                    rt[i] = v.x; pe[i] = v.y;
                }
#pragma unroll
                for (int i = 0; i < KB; ++i) {
                    float l1  = __builtin_amdgcn_logf(sm);
                    float sw  = fminf(__builtin_amdgcn_exp2f(fmaf(bBETA, l1, bB1)), 1.0f);
                    float smp = sm + rt[i];
                    float sm1 = fmaf(-rt[i], sw, smp);
                    float rch = rt[i] * sw;
                    float sm2 = fminf(sm1, bFC);
                    float exc = fmaxf(sm1 - bFC, 0.0f);
                    float l2  = __builtin_amdgcn_logf(sm2);
                    float ef  = fminf(__builtin_amdgcn_exp2f(fmaf(bBETAET, l2, bB2)), 1.0f);
                    float sm3 = fmaxf(fmaf(-pe[i], ef, sm2), NEARZERO);
                    float d   = fmaxf(fmaf(-bInvFC, sm3, 1.0f), 0.0f);
                    float cz  = bC * slz;
                    float cap = cz * d;           // == min(slz, cz*d): C<=1, d<=1
                    sm = sm3 + cap;
                    float slz1 = fmaxf(slz - cap, NEARZERO);
                    float su1 = suz + rch + exc;
                    float pa  = fminf(su1, bPERC);
                    float su2 = su1 - pa;
                    float q0  = bK0 * fmaxf(su2 - bUZL, 0.0f);
                    float su3 = su2 - q0;
                    float q1  = bK1 * su3;
                    suz = su3 - q1;
                    float sl2 = slz1 + pa;
                    float q2  = bK2 * sl2;
                    slz = sl2 - q2;
                    q_buf[slot][i][lane] = (q0 + q1) + q2;
                }
            }
        } else {
            // section C1: store LAST round's outputs first (guard phantom tail)
            if (m >= 4 && m <= NBLK + 3) {
                int bs = m - 4;
#pragma unroll
                for (int i = 0; i < KB; ++i) {
                    int t = bs * KB + i;
                    if (t < NSTEPS) out[(size_t)t * NGRID + g] = outv[i];
                }
            }
            __builtin_amdgcn_sched_barrier(0);
            // section C2: FIR for block m-3 into the register out-buffer
            if (m >= 3 && m <= NBLK + 2) {
                int b = m - 3, slot = b & 1;
                float qv[KB];
#pragma unroll
                for (int i = 0; i < KB; ++i) qv[i] = q_buf[slot][i][lane];
#pragma unroll
                for (int i = 0; i < KB; ++i) {
                    float q = qv[i];
                    outv[i] = fmaf(w[0], q, r[0]);
#pragma unroll
                    for (int j = 0; j < LENF - 2; ++j)
                        r[j] = fmaf(w[j + 1], q, r[j + 1]);
                    r[LENF - 2] = w[LENF - 1] * q;
                }
            }
        }
        __syncthreads();
    }
}

extern "C" void kernel_launch(void* const* d_in, const int* in_sizes, int n_in,
                              void* d_out, int out_size, void* d_ws, size_t ws_size,
                              hipStream_t stream) {
    const float* x_phy      = (const float*)d_in[0]; // f32 (730,10000,3)
    const float* phy_static = (const float*)d_in[1]; // f32 (10000,16)
    float* out = (float*)d_out;                      // f32 (730,10000)

    int nwg = (NGRID + 63) / 64;  // 157 workgroups x 192 threads (3 waves)
    hbv_pipe3<<<nwg, 192, 0, stream>>>(x_phy, phy_static, out);
}

// Round 15
// 201.893 us; speedup vs baseline: 1.6614x; 1.0111x over previous
//
#include <hip/hip_runtime.h>

#define NSTEPS 730
#define NGRID  10000
#define LENF   15
#define NEARZERO 1e-5f
#define KB 10            // steps per pipeline block
#define NBLK 73          // 730 = 73 * 10
#define NROUND (NBLK + 4)

struct F3 { float p, t, e; };  // (prcp, tmean, pet), 12B

// exp2 with fused [0,1] clamp (VOP3 clamp modifier): replaces
// fminf(exp2(y),1) -- one dependent op instead of two. Result of v_exp is
// >=0 so clamp==min(.,1). Trans->VALU deps are HW-interlocked (all prior
// rounds issued v_exp -> v_min back-to-back with no nops).
__device__ __forceinline__ float exp2_clamp01(float y) {
    float r;
    asm("v_exp_f32_e64 %0, %1 clamp" : "=v"(r) : "v"(y));
    return r;
}

// R7 skeleton (best verified: 105us) with the soil carried cycle cut from
// 16 to 12 dependent ops. Model (fits R7 HW-trans AND R8 ALU-pow at the
// same 345 cy/step): dep-ALU ~9.6cy, dep-trans ~57cy at 1 wave/SIMD.
// Wall time = 730 x chain latency (cells fully parallel; KB=20 and all
// sync/structure variants changed nothing -> chain-bound). Cuts:
//  - exp2_clamp01 fuses the two fminf(.,1) into the exps      (-2 deps)
//  - capillary: sm' = max(fma(km,sm3,cz), sm3), km=1-cz/FC,
//    cz=C*slz computed OFF-chain (slz ready ~80cy into the step,
//    needed ~270cy in); cap = sm'-sm3 reconstructs slz update  (-2 deps)
// New cycle: log,fma,expC,fma,min,log,fma,expC,fma,max,fma,max = 4T+8A
// ~ 305 cy/step ~ 93us predicted.
//
//   Wave A: batch input prefetch (reg double-buffer) + snow chain -> LDS
//   Wave B: soil/runoff chain (the carried cycle)                -> LDS
//   Wave C: transposed-FIR gamma routing, stores DELAYED one round
// Skew: A loads m; A snows m-1; B soils m-2; C FIRs m-3; C stores m-4.
__global__ __launch_bounds__(192, 1) void hbv_pipe3(const float* __restrict__ xp,
                                                    const float* __restrict__ ps,
                                                    float* __restrict__ out) {
    __shared__ float2 rtpe_buf[2][KB][64];  // A -> B : (rain+tosoil, pet)
    __shared__ float  q_buf[2][KB][64];     // B -> C : q

    const int lane = threadIdx.x & 63;
    const int wid  = threadIdx.x >> 6;
    int g = blockIdx.x * 64 + lane;
    g = (g < NGRID) ? g : (NGRID - 1);      // clamp: dup work, benign
    const int pb = g * 16;
    const F3* __restrict__ xv = (const F3*)xp;

    // ---- role A state ----
    float aTT = 0, aCFMAX = 0, aCFRxCFMAX = 0, aCWH = 0;
    float snow = NEARZERO, melt = NEARZERO;
    F3 abufA[KB], abufB[KB];               // static names only (no runtime idx)
    // ---- role B state ----
    float bFC = 0, bBETA = 0, bB1 = 0, bBETAET = 0, bB2 = 0, bInvFC = 0,
          bC = 0, bPERC = 0, bK0 = 0, bK1 = 0, bK2 = 0, bUZL = 0;
    float sm = NEARZERO, suz = NEARZERO, slz = NEARZERO;
    // ---- role C state ----
    float w[LENF];
    float r[LENF - 1];
    float outv[KB];

    if (wid == 0) {
        aTT        = ps[pb + 8]  * 5.0f - 2.5f;
        aCFMAX     = ps[pb + 9]  * 9.5f + 0.5f;
        aCFRxCFMAX = (ps[pb + 10] * 0.1f) * aCFMAX;
        aCWH       = ps[pb + 11] * 0.2f;
    } else if (wid == 1) {
        bFC     = ps[pb + 1]  * 950.0f + 50.0f;
        bBETA   = ps[pb + 0]  * 5.0f   + 1.0f;
        float LP = ps[pb + 5] * 0.8f   + 0.2f;
        bBETAET = ps[pb + 12] * 4.7f   + 0.3f;
        bInvFC  = 1.0f / bFC;
        // fold the argument scaling into the log: log2(x/FC)=log2(x)-log2(FC)
        bB1 = -bBETA   * __builtin_amdgcn_logf(bFC);
        bB2 = -bBETAET * __builtin_amdgcn_logf(LP * bFC);
        bC   = ps[pb + 13];
        bPERC = ps[pb + 6] * 10.0f;
        bK0  = ps[pb + 2] * 0.85f  + 0.05f;
        bK1  = ps[pb + 3] * 0.49f  + 0.01f;
        bK2  = ps[pb + 4] * 0.199f + 0.001f;
        bUZL = ps[pb + 7] * 100.0f;
    } else {
        // routing weights; -lgamma(aa)-aa*log(theta) cancel under normalization
        const float LOG2E = 1.4426950408889634f;
        float aa    = fmaxf(ps[pb + 14] * 2.9f, 0.0f) + 0.1f;
        float theta = fmaxf(ps[pb + 15] * 6.5f, 0.0f) + 0.5f;
        float sc = LOG2E / theta, am1 = aa - 1.0f, wsum = 0.0f;
#pragma unroll
        for (int k = 0; k < LENF; ++k) {
            float tg = (float)k + 0.5f;
            w[k] = __builtin_amdgcn_exp2f(am1 * __builtin_amdgcn_logf(tg) - tg * sc);
            wsum += w[k];
        }
        float inv = 1.0f / wsum;
#pragma unroll
        for (int k = 0; k < LENF; ++k) w[k] *= inv;
#pragma unroll
        for (int j = 0; j < LENF - 1; ++j) r[j] = 0.0f;
    }

    // batch prefetch of one input block into a register buffer
    auto LOADIN = [&](F3* buf, int blk) {
#pragma unroll
        for (int i = 0; i < KB; ++i)
            buf[i] = xv[(size_t)(blk * KB + i) * NGRID + g];
    };
    // snow chain for one block (consumes a register buffer loaded last round)
    auto SNOW = [&](const F3* in, int b) {
        float2 (*rp)[64] = rtpe_buf[b & 1];
#pragma unroll
        for (int i = 0; i < KB; ++i) {
            float p = in[i].p, tm = in[i].t;
            float dt = tm - aTT;
            float rain = (dt >= 0.0f) ? p : 0.0f;
            float mm = fmaxf(aCFMAX * dt, 0.0f);
            float rr = fmaxf(-aCFRxCFMAX * dt, 0.0f);   // == aCFRxCFMAX*(aTT-tm)
            snow += p - rain;
            float mq = fminf(mm, snow);
            melt += mq; snow -= mq;
            float refr = fminf(rr, melt);
            snow += refr; melt -= refr;
            float tosoil = fmaxf(fmaf(-aCWH, snow, melt), 0.0f);
            melt -= tosoil;
            rp[i][lane] = make_float2(rain + tosoil, in[i].e);
        }
    };

    for (int m = 0; m < NROUND; ++m) {
        if (wid == 0) {
            // section A1: issue next block's 10 loads FIRST (old by barrier)
            if (m < NBLK) {
                if ((m & 1) == 0) LOADIN(abufA, m);
                else              LOADIN(abufB, m);
            }
            __builtin_amdgcn_sched_barrier(0);
            // section A2: snow chain on the block loaded LAST round
            if (m >= 1 && m <= NBLK) {
                int b = m - 1;
                if ((b & 1) == 0) SNOW(abufA, b);
                else              SNOW(abufB, b);
            }
        } else if (wid == 1) {
            if (m >= 2 && m <= NBLK + 1) {
                int b = m - 2, slot = b & 1;
                float rt[KB], pe[KB];
#pragma unroll
                for (int i = 0; i < KB; ++i) {
                    float2 v = rtpe_buf[slot][i][lane];
                    rt[i] = v.x; pe[i] = v.y;
                }
#pragma unroll
                for (int i = 0; i < KB; ++i) {
                    // off-chain (needs slz, ready ~80cy into the step;
                    // consumed ~270cy in -- never critical):
                    float cz  = bC * slz;
                    float km  = fmaf(-cz, bInvFC, 1.0f);  // 1 - cz/FC
                    // ---- carried cycle: 4 trans + 8 ALU deps ----
                    float l1  = __builtin_amdgcn_logf(sm);
                    float sw  = exp2_clamp01(fmaf(bBETA, l1, bB1));
                    float smp = sm + rt[i];               // parallel to log/exp
                    float sm1 = fmaf(-rt[i], sw, smp);
                    float sm2 = fminf(sm1, bFC);
                    float l2  = __builtin_amdgcn_logf(sm2);
                    float ef  = exp2_clamp01(fmaf(bBETAET, l2, bB2));
                    float sm3 = fmaxf(fmaf(-pe[i], ef, sm2), NEARZERO);
                    float v2  = fmaf(km, sm3, cz);        // sm3 + cz*(1-sm3/FC)
                    float smn = fmaxf(v2, sm3);           // == sm3 + cap
                    // ---- off-chain tail ----
                    float cap = smn - sm3;                // exact cap
                    sm = smn;
                    float rch = rt[i] * sw;
                    float exc = fmaxf(sm1 - bFC, 0.0f);
                    float slz1 = fmaxf(slz - cap, NEARZERO);
                    float su1 = suz + rch + exc;
                    float pa  = fminf(su1, bPERC);
                    float su2 = su1 - pa;
                    float q0  = bK0 * fmaxf(su2 - bUZL, 0.0f);
                    float su3 = su2 - q0;
                    float q1  = bK1 * su3;
                    suz = su3 - q1;
                    float sl2 = slz1 + pa;
                    float q2  = bK2 * sl2;
                    slz = sl2 - q2;
                    q_buf[slot][i][lane] = (q0 + q1) + q2;
                }
            }
        } else {
            // section C1: store LAST round's outputs first (old by barrier)
            if (m >= 4 && m <= NBLK + 3) {
                int bs = m - 4;
#pragma unroll
                for (int i = 0; i < KB; ++i)
                    out[(size_t)(bs * KB + i) * NGRID + g] = outv[i];
            }
            __builtin_amdgcn_sched_barrier(0);
            // section C2: FIR for block m-3 into the register out-buffer
            if (m >= 3 && m <= NBLK + 2) {
                int b = m - 3, slot = b & 1;
                float qv[KB];
#pragma unroll
                for (int i = 0; i < KB; ++i) qv[i] = q_buf[slot][i][lane];
#pragma unroll
                for (int i = 0; i < KB; ++i) {
                    float q = qv[i];
                    outv[i] = fmaf(w[0], q, r[0]);
#pragma unroll
                    for (int j = 0; j < LENF - 2; ++j)
                        r[j] = fmaf(w[j + 1], q, r[j + 1]);
                    r[LENF - 2] = w[LENF - 1] * q;
                }
            }
        }
        __syncthreads();
    }
}

extern "C" void kernel_launch(void* const* d_in, const int* in_sizes, int n_in,
                              void* d_out, int out_size, void* d_ws, size_t ws_size,
                              hipStream_t stream) {
    const float* x_phy      = (const float*)d_in[0]; // f32 (730,10000,3)
    const float* phy_static = (const float*)d_in[1]; // f32 (10000,16)
    float* out = (float*)d_out;                      // f32 (730,10000)

    int nwg = (NGRID + 63) / 64;  // 157 workgroups x 192 threads (3 waves)
    hbv_pipe3<<<nwg, 192, 0, stream>>>(x_phy, phy_static, out);
}

// Round 16
// 201.265 us; speedup vs baseline: 1.6666x; 1.0031x over previous
//
#include <hip/hip_runtime.h>

#define NSTEPS 730
#define NGRID  10000
#define LENF   15
#define NEARZERO 1e-5f
#define KB 10            // steps per pipeline block
#define NBLK 73          // 730 = 73 * 10
#define NROUND (NBLK + 4)

struct F3 { float p, t, e; };  // (prcp, tmean, pet), 12B

// exp2 with fused [0,1] clamp (VOP3 clamp modifier): one dependent op for
// fminf(exp2(y),1). Result of v_exp >= 0 so clamp == min(.,1).
__device__ __forceinline__ float exp2_clamp01(float y) {
    float r;
    asm("v_exp_f32_e64 %0, %1 clamp" : "=v"(r) : "v"(y));
    return r;
}

// R15 skeleton + PARALLEL-POW predictor. 15 rounds of evidence condensed:
// per-step cost pinned at ~345cy across every structure; R15 (-4 ALU deps)
// and R8 (all-ALU pow, issue-bound coincidence) bracket the model to
// L_trans(dep) ~ 80cy, ALU links hidden -> chain = 4 x L_t serial through
//   log(sm) -> exp(sw) -> sm1 -> log(sm2) -> exp(ef).
// The serialization is ONLY via sw in sm1 = smp - rt*sw. Predictor: feed
// the ef-pow sm1p = smp - rt*sw_prev (one-step-stale sw; exact sw still
// updates sm). Both pows now run in parallel: path ~ 250cy/step.
// Numerics: d(sm2p) <= rt*|dsw| (~<=3 worst case) -> ef err ~1-3% ->
// etact err <=~0.1/step, contractive feedback, K-damped into Q.
// sw_pred init computed EXACTLY for sm=NEARZERO.
//
//   Wave A: batch input prefetch (reg double-buffer) + snow chain -> LDS
//   Wave B: soil/runoff chain (the carried cycle)                -> LDS
//   Wave C: transposed-FIR gamma routing, stores DELAYED one round
// Skew: A loads m; A snows m-1; B soils m-2; C FIRs m-3; C stores m-4.
__global__ __launch_bounds__(192, 1) void hbv_pipe3(const float* __restrict__ xp,
                                                    const float* __restrict__ ps,
                                                    float* __restrict__ out) {
    __shared__ float2 rtpe_buf[2][KB][64];  // A -> B : (rain+tosoil, pet)
    __shared__ float  q_buf[2][KB][64];     // B -> C : q

    const int lane = threadIdx.x & 63;
    const int wid  = threadIdx.x >> 6;
    int g = blockIdx.x * 64 + lane;
    g = (g < NGRID) ? g : (NGRID - 1);      // clamp: dup work, benign
    const int pb = g * 16;
    const F3* __restrict__ xv = (const F3*)xp;

    // ---- role A state ----
    float aTT = 0, aCFMAX = 0, aCFRxCFMAX = 0, aCWH = 0;
    float snow = NEARZERO, melt = NEARZERO;
    F3 abufA[KB], abufB[KB];               // static names only (no runtime idx)
    // ---- role B state ----
    float bFC = 0, bBETA = 0, bB1 = 0, bBETAET = 0, bB2 = 0, bInvFC = 0,
          bC = 0, bPERC = 0, bK0 = 0, bK1 = 0, bK2 = 0, bUZL = 0;
    float sm = NEARZERO, suz = NEARZERO, slz = NEARZERO;
    float sw_pred = 0.0f;                  // previous step's soil-wetness
    // ---- role C state ----
    float w[LENF];
    float r[LENF - 1];
    float outv[KB];

    if (wid == 0) {
        aTT        = ps[pb + 8]  * 5.0f - 2.5f;
        aCFMAX     = ps[pb + 9]  * 9.5f + 0.5f;
        aCFRxCFMAX = (ps[pb + 10] * 0.1f) * aCFMAX;
        aCWH       = ps[pb + 11] * 0.2f;
    } else if (wid == 1) {
        bFC     = ps[pb + 1]  * 950.0f + 50.0f;
        bBETA   = ps[pb + 0]  * 5.0f   + 1.0f;
        float LP = ps[pb + 5] * 0.8f   + 0.2f;
        bBETAET = ps[pb + 12] * 4.7f   + 0.3f;
        bInvFC  = 1.0f / bFC;
        // fold the argument scaling into the log: log2(x/FC)=log2(x)-log2(FC)
        bB1 = -bBETA   * __builtin_amdgcn_logf(bFC);
        bB2 = -bBETAET * __builtin_amdgcn_logf(LP * bFC);
        bC   = ps[pb + 13];
        bPERC = ps[pb + 6] * 10.0f;
        bK0  = ps[pb + 2] * 0.85f  + 0.05f;
        bK1  = ps[pb + 3] * 0.49f  + 0.01f;
        bK2  = ps[pb + 4] * 0.199f + 0.001f;
        bUZL = ps[pb + 7] * 100.0f;
        // exact sw for the initial state sm = NEARZERO
        sw_pred = exp2_clamp01(fmaf(bBETA, __builtin_amdgcn_logf(NEARZERO), bB1));
    } else {
        // routing weights; -lgamma(aa)-aa*log(theta) cancel under normalization
        const float LOG2E = 1.4426950408889634f;
        float aa    = fmaxf(ps[pb + 14] * 2.9f, 0.0f) + 0.1f;
        float theta = fmaxf(ps[pb + 15] * 6.5f, 0.0f) + 0.5f;
        float sc = LOG2E / theta, am1 = aa - 1.0f, wsum = 0.0f;
#pragma unroll
        for (int k = 0; k < LENF; ++k) {
            float tg = (float)k + 0.5f;
            w[k] = __builtin_amdgcn_exp2f(am1 * __builtin_amdgcn_logf(tg) - tg * sc);
            wsum += w[k];
        }
        float inv = 1.0f / wsum;
#pragma unroll
        for (int k = 0; k < LENF; ++k) w[k] *= inv;
#pragma unroll
        for (int j = 0; j < LENF - 1; ++j) r[j] = 0.0f;
    }

    // batch prefetch of one input block into a register buffer
    auto LOADIN = [&](F3* buf, int blk) {
#pragma unroll
        for (int i = 0; i < KB; ++i)
            buf[i] = xv[(size_t)(blk * KB + i) * NGRID + g];
    };
    // snow chain for one block (consumes a register buffer loaded last round)
    auto SNOW = [&](const F3* in, int b) {
        float2 (*rp)[64] = rtpe_buf[b & 1];
#pragma unroll
        for (int i = 0; i < KB; ++i) {
            float p = in[i].p, tm = in[i].t;
            float dt = tm - aTT;
            float rain = (dt >= 0.0f) ? p : 0.0f;
            float mm = fmaxf(aCFMAX * dt, 0.0f);
            float rr = fmaxf(-aCFRxCFMAX * dt, 0.0f);   // == aCFRxCFMAX*(aTT-tm)
            snow += p - rain;
            float mq = fminf(mm, snow);
            melt += mq; snow -= mq;
            float refr = fminf(rr, melt);
            snow += refr; melt -= refr;
            float tosoil = fmaxf(fmaf(-aCWH, snow, melt), 0.0f);
            melt -= tosoil;
            rp[i][lane] = make_float2(rain + tosoil, in[i].e);
        }
    };

    for (int m = 0; m < NROUND; ++m) {
        if (wid == 0) {
            // section A1: issue next block's 10 loads FIRST (old by barrier)
            if (m < NBLK) {
                if ((m & 1) == 0) LOADIN(abufA, m);
                else              LOADIN(abufB, m);
            }
            __builtin_amdgcn_sched_barrier(0);
            // section A2: snow chain on the block loaded LAST round
            if (m >= 1 && m <= NBLK) {
                int b = m - 1;
                if ((b & 1) == 0) SNOW(abufA, b);
                else              SNOW(abufB, b);
            }
        } else if (wid == 1) {
            if (m >= 2 && m <= NBLK + 1) {
                int b = m - 2, slot = b & 1;
                float rt[KB], pe[KB];
#pragma unroll
                for (int i = 0; i < KB; ++i) {
                    float2 v = rtpe_buf[slot][i][lane];
                    rt[i] = v.x; pe[i] = v.y;
                }
#pragma unroll
                for (int i = 0; i < KB; ++i) {
                    // off-chain (depends on slz only):
                    float cz  = bC * slz;
                    float km  = fmaf(-cz, bInvFC, 1.0f);  // 1 - cz/FC
                    // ---- parallel pow pair ----
                    // ef path (PREDICTED input, stale sw): ready early
                    float smp  = sm + rt[i];
                    float sm1p = fmaf(-rt[i], sw_pred, smp);
                    float sm2p = fminf(sm1p, bFC);
                    float l2   = __builtin_amdgcn_logf(sm2p);
                    float ef   = exp2_clamp01(fmaf(bBETAET, l2, bB2));
                    // sw path (EXACT):
                    float l1  = __builtin_amdgcn_logf(sm);
                    float sw  = exp2_clamp01(fmaf(bBETA, l1, bB1));
                    float sm1 = fmaf(-rt[i], sw, smp);
                    float sm2 = fminf(sm1, bFC);
                    // ---- join ----
                    float sm3 = fmaxf(fmaf(-pe[i], ef, sm2), NEARZERO);
                    float v2  = fmaf(km, sm3, cz);        // sm3 + cz*(1-sm3/FC)
                    float smn = fmaxf(v2, sm3);           // == sm3 + cap
                    // ---- off-chain tail ----
                    float cap = smn - sm3;                // exact cap
                    sm = smn;
                    sw_pred = sw;                         // carry for next step
                    float rch = rt[i] * sw;
                    float exc = fmaxf(sm1 - bFC, 0.0f);
                    float slz1 = fmaxf(slz - cap, NEARZERO);
                    float su1 = suz + rch + exc;
                    float pa  = fminf(su1, bPERC);
                    float su2 = su1 - pa;
                    float q0  = bK0 * fmaxf(su2 - bUZL, 0.0f);
                    float su3 = su2 - q0;
                    float q1  = bK1 * su3;
                    suz = su3 - q1;
                    float sl2 = slz1 + pa;
                    float q2  = bK2 * sl2;
                    slz = sl2 - q2;
                    q_buf[slot][i][lane] = (q0 + q1) + q2;
                }
            }
        } else {
            // section C1: store LAST round's outputs first (old by barrier)
            if (m >= 4 && m <= NBLK + 3) {
                int bs = m - 4;
#pragma unroll
                for (int i = 0; i < KB; ++i)
                    out[(size_t)(bs * KB + i) * NGRID + g] = outv[i];
            }
            __builtin_amdgcn_sched_barrier(0);
            // section C2: FIR for block m-3 into the register out-buffer
            if (m >= 3 && m <= NBLK + 2) {
                int b = m - 3, slot = b & 1;
                float qv[KB];
#pragma unroll
                for (int i = 0; i < KB; ++i) qv[i] = q_buf[slot][i][lane];
#pragma unroll
                for (int i = 0; i < KB; ++i) {
                    float q = qv[i];
                    outv[i] = fmaf(w[0], q, r[0]);
#pragma unroll
                    for (int j = 0; j < LENF - 2; ++j)
                        r[j] = fmaf(w[j + 1], q, r[j + 1]);
                    r[LENF - 2] = w[LENF - 1] * q;
                }
            }
        }
        __syncthreads();
    }
}

extern "C" void kernel_launch(void* const* d_in, const int* in_sizes, int n_in,
                              void* d_out, int out_size, void* d_ws, size_t ws_size,
                              hipStream_t stream) {
    const float* x_phy      = (const float*)d_in[0]; // f32 (730,10000,3)
    const float* phy_static = (const float*)d_in[1]; // f32 (10000,16)
    float* out = (float*)d_out;                      // f32 (730,10000)

    int nwg = (NGRID + 63) / 64;  // 157 workgroups x 192 threads (3 waves)
    hbv_pipe3<<<nwg, 192, 0, stream>>>(x_phy, phy_static, out);
}